// Round 1
// 509.728 us; speedup vs baseline: 1.0590x; 1.0590x over previous
//
#include <hip/hip_runtime.h>
#include <stdint.h>

#define M_DIM 4096
#define K_DIM 4096
#define N_DIM 11008

typedef int v4i __attribute__((ext_vector_type(4)));

// Address-space casts via uintptr_t (composable_kernel pattern).
#define LDSP(p) ((__attribute__((address_space(3))) void*)(uintptr_t)(p))
#define GLBP(p) ((__attribute__((address_space(1))) void*)(uintptr_t)(p))

// ---------------------------------------------------------------------------
// Kernel 1: per-row dynamic quantization of x (fp32 -> int8) + row scale.
// (unchanged — ~13 µs, memory-bound)
// ---------------------------------------------------------------------------
__global__ __launch_bounds__(256) void quant_rows(const float* __restrict__ x,
                                                  int8_t* __restrict__ xq,
                                                  float* __restrict__ xs_out) {
    const int row = blockIdx.x;
    const int t = threadIdx.x;
    const float4* xr = (const float4*)(x + (size_t)row * K_DIM);

    float4 v[4];
    float amax = 0.0f;
#pragma unroll
    for (int r = 0; r < 4; ++r) {
        v[r] = xr[t + r * 256];
        amax = fmaxf(amax, fmaxf(fmaxf(fabsf(v[r].x), fabsf(v[r].y)),
                                 fmaxf(fabsf(v[r].z), fabsf(v[r].w))));
    }
#pragma unroll
    for (int off = 32; off > 0; off >>= 1)
        amax = fmaxf(amax, __shfl_xor(amax, off));

    __shared__ float smax[4];
    if ((t & 63) == 0) smax[t >> 6] = amax;
    __syncthreads();
    amax = fmaxf(fmaxf(smax[0], smax[1]), fmaxf(smax[2], smax[3]));

    const float xs = fmaxf(amax / 127.0f, 1e-8f);
    if (t == 0) xs_out[row] = xs;

    int* qo = (int*)(xq + (size_t)row * K_DIM);
#pragma unroll
    for (int r = 0; r < 4; ++r) {
        int q0 = (int)rintf(v[r].x / xs);
        int q1 = (int)rintf(v[r].y / xs);
        int q2 = (int)rintf(v[r].z / xs);
        int q3 = (int)rintf(v[r].w / xs);
        q0 = min(127, max(-128, q0));
        q1 = min(127, max(-128, q1));
        q2 = min(127, max(-128, q2));
        q3 = min(127, max(-128, q3));
        int packed = (q0 & 255) | ((q1 & 255) << 8) | ((q2 & 255) << 16) | (q3 << 24);
        qo[t + r * 256] = packed;
    }
}

// ---------------------------------------------------------------------------
// Kernel 2: normalize weight into contiguous int8 in workspace (unchanged).
// ---------------------------------------------------------------------------
__global__ __launch_bounds__(256) void prep_weight(const void* __restrict__ wraw,
                                                   int8_t* __restrict__ w8) {
    const int* wi = (const int*)wraw;
    int c = 0;
#pragma unroll
    for (int i = 0; i < 64; ++i) {
        int w = wi[i];
        c += (w >= -128 && w <= 127) ? 1 : 0;
    }
    const size_t tid = (size_t)blockIdx.x * 256 + threadIdx.x;  // 16 bytes each
    if (c >= 32) {
        union { int4 v; char b[16]; } o;
#pragma unroll
        for (int g = 0; g < 4; ++g) {
            int4 w = ((const int4*)wraw)[tid * 4 + g];
            o.b[g * 4 + 0] = (char)w.x;
            o.b[g * 4 + 1] = (char)w.y;
            o.b[g * 4 + 2] = (char)w.z;
            o.b[g * 4 + 3] = (char)w.w;
        }
        ((int4*)w8)[tid] = o.v;
    } else {
        ((int4*)w8)[tid] = ((const int4*)wraw)[tid];
    }
}

// ---------------------------------------------------------------------------
// Kernel 3: int8 GEMM — 256x256 tile, BK=128, 8-phase counted-vmcnt schedule
// (T2 XOR swizzle + T3/T4 8-phase counted vmcnt + T5 setprio + T1 XCD swizzle).
//
// Geometry: 512 threads = 8 waves (2M x 4N); per-wave output 128x64 =
// 8 M-frags x 4 N-frags of mfma_i32_16x16x64_i8; BK=128 bytes = 2 k-steps.
// LDS: A,B tiles 256x128 B, double-buffered = 128 KiB. Tile 2p -> buf0,
// tile 2p+1 -> buf1 (static buffer roles, no pointer flip).
//
// Per-phase schedule (iteration p; T2 = tile 2p+2, T3 = tile 2p+3):
//   ph1: read B(c0)[all j, k0+k1] + A(c0)[0-3][k0]   | -            | MFMA i0-3,k0
//   ph2: read A(c0)[4-7][k0]                          | st Bh0(c0)   | MFMA i4-7,k0
//   ph3: read A(c0)[0-7][k1]                          | st Bh1(c0)   | MFMA i0-3,k1
//   ph4: -                                            | st Ah0(c0)+vmcnt(6) | MFMA i4-7,k1
//   ph5..ph8: same on buf1; ph8 stages Ah0(c1)+Ah1(c1) then vmcnt(6).
// vmcnt(6) = 3 half-tiles (6 loads) in flight — guarantees the tile read 4
// phases later has fully landed. Each compute phase fully retires exactly the
// half-tile restaged one phase later (B front-loaded at ph1/ph5; A k1 at
// ph3/ph7). Raw s_barrier (NOT __syncthreads) so loads survive barriers.
// Last iteration peeled: no stages, vmcnt(0) at ph4.
// ---------------------------------------------------------------------------
__global__ __launch_bounds__(512, 2) void w8a8_gemm(const int8_t* __restrict__ xq,
                                                    const float* __restrict__ xscale,
                                                    const int8_t* __restrict__ wgt,
                                                    const float* __restrict__ wscale,
                                                    const float* __restrict__ bias,
                                                    float* __restrict__ out) {
    __shared__ __align__(16) int8_t lds_a[2][256 * 128];  // 64 KB
    __shared__ __align__(16) int8_t lds_b[2][256 * 128];  // 64 KB

    const int t = threadIdx.x;
    const int lane = t & 63;
    const int wave = t >> 6;   // 0..7
    const int wm = wave >> 2;  // 0..1  (M half)
    const int wn = wave & 3;   // 0..3  (N quarter)
    const int quad = lane >> 4;
    const int l15 = lane & 15;

    // T1: XCD-aware swizzle. 688 blocks = 8 XCDs x 86; each XCD gets a
    // contiguous chunk; bm varies slowest so an XCD's L2 keeps ~3 A-panels.
    const int wg = blockIdx.x;
    const int swz = (wg & 7) * 86 + (wg >> 3);
    const int bm = swz / 43;  // 0..15
    const int bn = swz % 43;  // 0..42

    const int8_t* pa = xq + (size_t)bm * 256 * K_DIM;
    const int8_t* pb = wgt + (size_t)bn * 256 * K_DIM;

    // Staging: thread t covers LDS (row = g*64 + (t>>3), 16B-chunk = t&7) of a
    // 128-row half-tile. Global source chunk pre-XOR'd so a linear LDS write +
    // XOR'd read = swizzle (rule: both-sides-or-neither with global_load_lds).
    const int srow = t >> 3;  // 0..63
    const size_t soff = (size_t)srow * K_DIM + (size_t)(((t & 7) ^ (srow & 7)) << 4);
    const size_t g1 = (size_t)64 * K_DIM;   // +64 rows (2nd 8KB group of a half)
    const size_t h1 = (size_t)128 * K_DIM;  // +128 rows (2nd half-tile)

#define STAGE_HALF(gb, lb)                                                               \
    do {                                                                                 \
        __builtin_amdgcn_global_load_lds(GLBP((gb) + soff), LDSP((lb) + t * 16), 16, 0, 0); \
        __builtin_amdgcn_global_load_lds(GLBP((gb) + soff + g1), LDSP((lb) + 8192 + t * 16), 16, 0, 0); \
    } while (0)

    // Fragment read offsets: row*128 + ((ks*4+quad) ^ (row&7))*16; row&7==l15&7.
    int abase[2], bbase[2];
#pragma unroll
    for (int ks = 0; ks < 2; ++ks) {
        const int ar = wm * 128 + l15;
        abase[ks] = ar * 128 + (((ks * 4 + quad) ^ (l15 & 7)) << 4);
        const int br = wn * 64 + l15;
        bbase[ks] = br * 128 + (((ks * 4 + quad) ^ (l15 & 7)) << 4);
    }

    int8_t* la0 = &lds_a[0][0];
    int8_t* la1 = &lds_a[1][0];
    int8_t* lb0 = &lds_b[0][0];
    int8_t* lb1 = &lds_b[1][0];

    v4i acc[8][4] = {};
    v4i af[8], bf[8];  // af: A frags (k-step rotates); bf[0-3]=k0, bf[4-7]=k1

#define READ_B(c)                                                     \
    _Pragma("unroll") for (int j = 0; j < 4; ++j) {                   \
        bf[j] = *(const v4i*)(&lds_b[c][bbase[0] + j * 2048]);        \
        bf[4 + j] = *(const v4i*)(&lds_b[c][bbase[1] + j * 2048]);    \
    }
#define READ_A4(c, ks, i0)                                            \
    _Pragma("unroll") for (int i = 0; i < 4; ++i)                     \
        af[(i0) + i] = *(const v4i*)(&lds_a[c][abase[ks] + ((i0) + i) * 2048]);
#define MFMA16(A0, B0)                                                \
    _Pragma("unroll") for (int i = 0; i < 4; ++i)                     \
    _Pragma("unroll") for (int j = 0; j < 4; ++j)                     \
        acc[(A0) + i][j] = __builtin_amdgcn_mfma_i32_16x16x64_i8(     \
            af[(A0) + i], bf[(B0) + j], acc[(A0) + i][j], 0, 0, 0);
#define PH_PRE                                                        \
    __builtin_amdgcn_s_barrier();                                     \
    asm volatile("s_waitcnt lgkmcnt(0)" ::: "memory");                \
    __builtin_amdgcn_s_setprio(1);
#define PH_POST                                                       \
    __builtin_amdgcn_s_setprio(0);                                    \
    __builtin_amdgcn_s_barrier();

    // ---- prologue: stage tiles 0 (buf0) and 1 (buf1); wait tile0 landed ----
    STAGE_HALF(pa, la0);
    STAGE_HALF(pa + h1, la0 + 16384);
    STAGE_HALF(pb, lb0);
    STAGE_HALF(pb + h1, lb0 + 16384);
    STAGE_HALF(pa + 128, la1);
    STAGE_HALF(pa + 128 + h1, la1 + 16384);
    STAGE_HALF(pb + 128, lb1);
    STAGE_HALF(pb + 128 + h1, lb1 + 16384);
    asm volatile("s_waitcnt vmcnt(8)" ::: "memory");  // tile0's 8 loads done
    __builtin_amdgcn_s_barrier();

#pragma unroll 1
    for (int p = 0; p < 16; ++p) {
        const bool st = (p < 15);
        const int8_t* qa = pa + (size_t)(2 * p + 2) * 128;  // tile 2p+2
        const int8_t* qb = pb + (size_t)(2 * p + 2) * 128;

        // ================= buf0 : tile 2p =================
        // ph1
        READ_B(0);
        READ_A4(0, 0, 0);
        PH_PRE; MFMA16(0, 0); PH_POST;
        // ph2
        READ_A4(0, 0, 4);
        if (st) STAGE_HALF(qb, lb0);
        PH_PRE; MFMA16(4, 0); PH_POST;
        // ph3
        READ_A4(0, 1, 0);
        READ_A4(0, 1, 4);
        if (st) STAGE_HALF(qb + h1, lb0 + 16384);
        PH_PRE; MFMA16(0, 4); PH_POST;
        // ph4
        if (st) {
            STAGE_HALF(qa, la0);
            asm volatile("s_waitcnt vmcnt(6)" ::: "memory");
        } else {
            asm volatile("s_waitcnt vmcnt(0)" ::: "memory");
        }
        PH_PRE; MFMA16(4, 4); PH_POST;

        // ================= buf1 : tile 2p+1 =================
        // ph5
        READ_B(1);
        READ_A4(1, 0, 0);
        if (st) STAGE_HALF(qa + h1, la0 + 16384);
        PH_PRE; MFMA16(0, 0); PH_POST;
        // ph6
        READ_A4(1, 0, 4);
        if (st) STAGE_HALF(qb + 128, lb1);
        PH_PRE; MFMA16(4, 0); PH_POST;
        // ph7
        READ_A4(1, 1, 0);
        READ_A4(1, 1, 4);
        if (st) STAGE_HALF(qb + 128 + h1, lb1 + 16384);
        PH_PRE; MFMA16(0, 4); PH_POST;
        // ph8
        if (st) {
            STAGE_HALF(qa + 128, la1);
            STAGE_HALF(qa + 128 + h1, la1 + 16384);
            asm volatile("s_waitcnt vmcnt(6)" ::: "memory");
        }
        PH_PRE; MFMA16(4, 4); PH_POST;
    }

    // --- epilogue: dequant + bias (layout carried from verified kernel) ---
    float wsc[4], bi[4];
#pragma unroll
    for (int j = 0; j < 4; ++j) {
        const int cc = bn * 256 + wn * 64 + j * 16 + l15;
        wsc[j] = wscale[cc];
        bi[j] = bias[cc];
    }
#pragma unroll
    for (int i = 0; i < 8; ++i) {
        const int m0 = bm * 256 + wm * 128 + i * 16 + quad * 4;  // 4-aligned
        const float4 xs4 = *(const float4*)(xscale + m0);
        const float xsv[4] = {xs4.x, xs4.y, xs4.z, xs4.w};
#pragma unroll
        for (int r = 0; r < 4; ++r) {
            const size_t off = (size_t)(m0 + r) * N_DIM + (size_t)bn * 256 + wn * 64 + l15;
#pragma unroll
            for (int j = 0; j < 4; ++j) {
                out[off + j * 16] = (float)acc[i][j][r] * xsv[r] * wsc[j] + bi[j];
            }
        }
    }
}

// ---------------------------------------------------------------------------
extern "C" void kernel_launch(void* const* d_in, const int* in_sizes, int n_in,
                              void* d_out, int out_size, void* d_ws, size_t ws_size,
                              hipStream_t stream) {
    const float* x = (const float*)d_in[0];
    const void* wraw = (const void*)d_in[1];
    const float* wscale = (const float*)d_in[2];
    const float* bias = (const float*)d_in[3];
    float* out = (float*)d_out;

    // workspace layout: [w8: N*K][xq: M*K][xs: M floats]
    int8_t* w8 = (int8_t*)d_ws;
    int8_t* xq = (int8_t*)d_ws + (size_t)N_DIM * K_DIM;
    float* xs = (float*)((char*)d_ws + (size_t)N_DIM * K_DIM + (size_t)M_DIM * K_DIM);

    quant_rows<<<M_DIM, 256, 0, stream>>>(x, xq, xs);
    prep_weight<<<(N_DIM * (K_DIM / 16)) / 256, 256, 0, stream>>>(wraw, w8);
    // 256x256 tiles: grid = (4096/256) x (11008/256) = 16 x 43 = 688 (1-D, swizzled)
    w8a8_gemm<<<688, 512, 0, stream>>>(xq, xs, w8, wscale, bias, out);
}

// Round 2
// 494.579 us; speedup vs baseline: 1.0914x; 1.0306x over previous
//
#include <hip/hip_runtime.h>
#include <stdint.h>

#define M_DIM 4096
#define K_DIM 4096
#define N_DIM 11008

typedef int v4i __attribute__((ext_vector_type(4)));

// Address-space casts via uintptr_t (composable_kernel pattern).
#define LDSP(p) ((__attribute__((address_space(3))) void*)(uintptr_t)(p))
#define GLBP(p) ((__attribute__((address_space(1))) void*)(uintptr_t)(p))

// ---------------------------------------------------------------------------
// Kernel 1: per-row dynamic quantization of x (fp32 -> int8) + row scale.
// (unchanged — memory-bound)
// ---------------------------------------------------------------------------
__global__ __launch_bounds__(256) void quant_rows(const float* __restrict__ x,
                                                  int8_t* __restrict__ xq,
                                                  float* __restrict__ xs_out) {
    const int row = blockIdx.x;
    const int t = threadIdx.x;
    const float4* xr = (const float4*)(x + (size_t)row * K_DIM);

    float4 v[4];
    float amax = 0.0f;
#pragma unroll
    for (int r = 0; r < 4; ++r) {
        v[r] = xr[t + r * 256];
        amax = fmaxf(amax, fmaxf(fmaxf(fabsf(v[r].x), fabsf(v[r].y)),
                                 fmaxf(fabsf(v[r].z), fabsf(v[r].w))));
    }
#pragma unroll
    for (int off = 32; off > 0; off >>= 1)
        amax = fmaxf(amax, __shfl_xor(amax, off));

    __shared__ float smax[4];
    if ((t & 63) == 0) smax[t >> 6] = amax;
    __syncthreads();
    amax = fmaxf(fmaxf(smax[0], smax[1]), fmaxf(smax[2], smax[3]));

    const float xs = fmaxf(amax / 127.0f, 1e-8f);
    if (t == 0) xs_out[row] = xs;

    int* qo = (int*)(xq + (size_t)row * K_DIM);
#pragma unroll
    for (int r = 0; r < 4; ++r) {
        int q0 = (int)rintf(v[r].x / xs);
        int q1 = (int)rintf(v[r].y / xs);
        int q2 = (int)rintf(v[r].z / xs);
        int q3 = (int)rintf(v[r].w / xs);
        q0 = min(127, max(-128, q0));
        q1 = min(127, max(-128, q1));
        q2 = min(127, max(-128, q2));
        q3 = min(127, max(-128, q3));
        int packed = (q0 & 255) | ((q1 & 255) << 8) | ((q2 & 255) << 16) | (q3 << 24);
        qo[t + r * 256] = packed;
    }
}

// ---------------------------------------------------------------------------
// Kernel 2: normalize weight into contiguous int8 in workspace (unchanged).
// ---------------------------------------------------------------------------
__global__ __launch_bounds__(256) void prep_weight(const void* __restrict__ wraw,
                                                   int8_t* __restrict__ w8) {
    const int* wi = (const int*)wraw;
    int c = 0;
#pragma unroll
    for (int i = 0; i < 64; ++i) {
        int w = wi[i];
        c += (w >= -128 && w <= 127) ? 1 : 0;
    }
    const size_t tid = (size_t)blockIdx.x * 256 + threadIdx.x;  // 16 bytes each
    if (c >= 32) {
        union { int4 v; char b[16]; } o;
#pragma unroll
        for (int g = 0; g < 4; ++g) {
            int4 w = ((const int4*)wraw)[tid * 4 + g];
            o.b[g * 4 + 0] = (char)w.x;
            o.b[g * 4 + 1] = (char)w.y;
            o.b[g * 4 + 2] = (char)w.z;
            o.b[g * 4 + 3] = (char)w.w;
        }
        ((int4*)w8)[tid] = o.v;
    } else {
        ((int4*)w8)[tid] = ((const int4*)wraw)[tid];
    }
}

// ---------------------------------------------------------------------------
// Kernel 3: int8 GEMM — 256x256 tile, BK=128, RING-BUFFERED deep pipeline.
//
// Round-1 post-mortem: delivery of staged bytes ran at 26 B/cy/CU (L2 ceiling
// 56, HBM 28% used) -> latency-bound on the L2-miss stream, with only 6
// loads/thread in flight at the vmcnt gates and a ~4-phase (~800cy) window.
//
// This version: A ring of 3 tiles + B ring of 2 tiles = 160 KiB LDS (chip
// max). Per-tile 2-phase schedule:
//   ph0(t): ds_read B(t)[all 8] + A(t)[k0, 8]; issue STAGE A(t+2)
//           (slot (t+2)%3 was retired at end of tile t-1); barrier;
//           lgkmcnt(0); 16 MFMA (k0); barrier.
//   ph1(t): ds_read A(t)[k1, 8]; issue STAGE B(t+2) (slot t%2, retired at
//           ph0(t)'s trailing barrier); vmcnt(8) <- gate for tile t+1
//           (8 newest = A(t+2)+B(t+2)); barrier; lgkmcnt(0); 16 MFMA (k1);
//           barrier.
// In-flight: 16 loads/thread peak, 8 post-gate (vs 10/6 before); A window
// ~3.5 phases (~1100cy), B ~2.5 (~800cy). Never vmcnt(0) in the loop; tail
// tiles 30/31 peeled with a single vmcnt(0).
//
// XCD swizzle reworked: bm varies FASTEST within an XCD chunk (bm = 2*xcd +
// (u&1), bn = u>>1) so the 32 co-resident blocks per XCD pair up on B panels
// (round 1: bn-fastest gave every XCD a full 45MB B miss -> FETCH 374MB).
// ---------------------------------------------------------------------------
__global__ __launch_bounds__(512, 2) void w8a8_gemm(const int8_t* __restrict__ xq,
                                                    const float* __restrict__ xscale,
                                                    const int8_t* __restrict__ wgt,
                                                    const float* __restrict__ wscale,
                                                    const float* __restrict__ bias,
                                                    float* __restrict__ out) {
    __shared__ __align__(16) int8_t lds_a[3][32768];  // 96 KB: A ring, 3 tiles
    __shared__ __align__(16) int8_t lds_b[2][32768];  // 64 KB: B ring, 2 tiles

    const int t = threadIdx.x;
    const int lane = t & 63;
    const int wave = t >> 6;   // 0..7
    const int wm = wave >> 2;  // 0..1  (M half)
    const int wn = wave & 3;   // 0..3  (N quarter)
    const int quad = lane >> 4;
    const int l15 = lane & 15;

    // XCD-aware swizzle, bm-fastest within chunk. 688 = 8 XCDs x 86 exactly.
    const int wg = blockIdx.x;
    const int xcd = wg & 7;
    const int u = wg >> 3;              // 0..85 within XCD
    const int bm = 2 * xcd + (u & 1);   // 0..15 (each XCD owns a bm pair)
    const int bn = u >> 1;              // 0..42

    const int8_t* pa = xq + (size_t)bm * 256 * K_DIM;
    const int8_t* pb = wgt + (size_t)bn * 256 * K_DIM;

    // Staging: thread t covers (row = g*64 + (t>>3), 16B-chunk = t&7) of the
    // 256x128 tile; 4 global_load_lds per tile. Source chunk pre-XOR'd so a
    // linear LDS write + XOR'd read = swizzle (both-sides-or-neither rule).
    const int srow = t >> 3;  // 0..63
    const size_t soff = (size_t)srow * K_DIM + (size_t)(((t & 7) ^ (srow & 7)) << 4);
    const size_t g64 = (size_t)64 * K_DIM;  // +64 rows

#define STAGE_TILE(gb, lb)                                                                   \
    do {                                                                                     \
        __builtin_amdgcn_global_load_lds(GLBP((gb) + soff), LDSP((lb) + t * 16), 16, 0, 0);  \
        __builtin_amdgcn_global_load_lds(GLBP((gb) + soff + g64), LDSP((lb) + 8192 + t * 16), 16, 0, 0); \
        __builtin_amdgcn_global_load_lds(GLBP((gb) + soff + 2 * g64), LDSP((lb) + 16384 + t * 16), 16, 0, 0); \
        __builtin_amdgcn_global_load_lds(GLBP((gb) + soff + 3 * g64), LDSP((lb) + 24576 + t * 16), 16, 0, 0); \
    } while (0)

    // Fragment read offsets: row*128 + ((ks*4+quad) ^ (row&7))*16; row&7==l15&7.
    int abase[2], bbase[2];
#pragma unroll
    for (int ks = 0; ks < 2; ++ks) {
        const int ar = wm * 128 + l15;
        abase[ks] = ar * 128 + (((ks * 4 + quad) ^ (l15 & 7)) << 4);
        const int br = wn * 64 + l15;
        bbase[ks] = br * 128 + (((ks * 4 + quad) ^ (l15 & 7)) << 4);
    }

    v4i acc[8][4] = {};
    v4i af[8], bf[8];  // af: current k-step's 8 M-frags; bf[0-3]=k0, bf[4-7]=k1

#define READ_B8(SB)                                                   \
    _Pragma("unroll") for (int j = 0; j < 4; ++j) {                   \
        bf[j] = *(const v4i*)(&lds_b[SB][bbase[0] + j * 2048]);       \
        bf[4 + j] = *(const v4i*)(&lds_b[SB][bbase[1] + j * 2048]);   \
    }
#define READ_A8(SA, KS)                                               \
    _Pragma("unroll") for (int i = 0; i < 8; ++i)                     \
        af[i] = *(const v4i*)(&lds_a[SA][abase[KS] + i * 2048]);
#define MFMA16(B0)                                                    \
    _Pragma("unroll") for (int i = 0; i < 8; ++i)                     \
    _Pragma("unroll") for (int j = 0; j < 4; ++j)                     \
        acc[i][j] = __builtin_amdgcn_mfma_i32_16x16x64_i8(            \
            af[i], bf[(B0) + j], acc[i][j], 0, 0, 0);
#define PH_PRE                                                        \
    __builtin_amdgcn_s_barrier();                                     \
    asm volatile("s_waitcnt lgkmcnt(0)" ::: "memory");                \
    __builtin_amdgcn_s_setprio(1);
#define PH_POST                                                       \
    __builtin_amdgcn_s_setprio(0);                                    \
    __builtin_amdgcn_s_barrier();

    // ---- prologue: stage tiles 0,1 (A slots 0,1 / B slots 0,1) ----
    STAGE_TILE(pa, &lds_a[0][0]);
    STAGE_TILE(pb, &lds_b[0][0]);
    STAGE_TILE(pa + 128, &lds_a[1][0]);
    STAGE_TILE(pb + 128, &lds_b[1][0]);
    asm volatile("s_waitcnt vmcnt(8)" ::: "memory");  // tile 0 (oldest 8) landed
    __builtin_amdgcn_s_barrier();

    // Steady tile: slots SA=t%3, SB=t%2; stage tile t+2 into SA2=(t+2)%3, SB.
#define DO_TILE(U)                                                       \
    {                                                                    \
        constexpr int SA = (U) % 3;                                      \
        constexpr int SB = (U) % 2;                                      \
        constexpr int SA2 = ((U) + 2) % 3;                               \
        const size_t k2 = (size_t)(t0 + (U) + 2) * 128;                  \
        /* ph0 */                                                        \
        READ_B8(SB);                                                     \
        READ_A8(SA, 0);                                                  \
        STAGE_TILE(pa + k2, &lds_a[SA2][0]);                             \
        PH_PRE; MFMA16(0); PH_POST;                                      \
        /* ph1 */                                                        \
        READ_A8(SA, 1);                                                  \
        STAGE_TILE(pb + k2, &lds_b[SB][0]);                              \
        asm volatile("s_waitcnt vmcnt(8)" ::: "memory");                 \
        PH_PRE; MFMA16(4); PH_POST;                                      \
    }

    // 32 K-tiles total; loop covers t = 0..29 (all stages legal: max t+2 = 31),
    // tiles 30,31 peeled with no stages.
#pragma unroll 1
    for (int t0 = 0; t0 < 30; t0 += 6) {
        DO_TILE(0)
        DO_TILE(1)
        DO_TILE(2)
        DO_TILE(3)
        DO_TILE(4)
        DO_TILE(5)
    }
    // t = 30 (SA=0, SB=0)
    READ_B8(0);
    READ_A8(0, 0);
    PH_PRE; MFMA16(0); PH_POST;
    READ_A8(0, 1);
    asm volatile("s_waitcnt vmcnt(0)" ::: "memory");  // tile 31 landed
    PH_PRE; MFMA16(4); PH_POST;
    // t = 31 (SA=1, SB=1)
    READ_B8(1);
    READ_A8(1, 0);
    PH_PRE; MFMA16(0); PH_POST;
    READ_A8(1, 1);
    PH_PRE; MFMA16(4); PH_POST;

    // --- epilogue: dequant + bias (unchanged math/layout) ---
    float wsc[4], bi[4];
#pragma unroll
    for (int j = 0; j < 4; ++j) {
        const int cc = bn * 256 + wn * 64 + j * 16 + l15;
        wsc[j] = wscale[cc];
        bi[j] = bias[cc];
    }
#pragma unroll
    for (int i = 0; i < 8; ++i) {
        const int m0 = bm * 256 + wm * 128 + i * 16 + quad * 4;  // 4-aligned
        const float4 xs4 = *(const float4*)(xscale + m0);
        const float xsv[4] = {xs4.x, xs4.y, xs4.z, xs4.w};
#pragma unroll
        for (int r = 0; r < 4; ++r) {
            const size_t off = (size_t)(m0 + r) * N_DIM + (size_t)bn * 256 + wn * 64 + l15;
#pragma unroll
            for (int j = 0; j < 4; ++j) {
                out[off + j * 16] = (float)acc[i][j][r] * xsv[r] * wsc[j] + bi[j];
            }
        }
    }
}

// ---------------------------------------------------------------------------
extern "C" void kernel_launch(void* const* d_in, const int* in_sizes, int n_in,
                              void* d_out, int out_size, void* d_ws, size_t ws_size,
                              hipStream_t stream) {
    const float* x = (const float*)d_in[0];
    const void* wraw = (const void*)d_in[1];
    const float* wscale = (const float*)d_in[2];
    const float* bias = (const float*)d_in[3];
    float* out = (float*)d_out;

    // workspace layout: [w8: N*K][xq: M*K][xs: M floats]
    int8_t* w8 = (int8_t*)d_ws;
    int8_t* xq = (int8_t*)d_ws + (size_t)N_DIM * K_DIM;
    float* xs = (float*)((char*)d_ws + (size_t)N_DIM * K_DIM + (size_t)M_DIM * K_DIM);

    quant_rows<<<M_DIM, 256, 0, stream>>>(x, xq, xs);
    prep_weight<<<(N_DIM * (K_DIM / 16)) / 256, 256, 0, stream>>>(wraw, w8);
    // 256x256 tiles: 16 x 43 = 688 blocks (1-D, XCD-swizzled)
    w8a8_gemm<<<688, 512, 0, stream>>>(xq, xs, w8, wscale, bias, out);
}